// Round 5
// baseline (3592.829 us; speedup 1.0000x reference)
//
#include <hip/hip_runtime.h>
#include <math.h>

#define B 16
#define N 1024
#define KNB 20

__device__ __forceinline__ float sgnf(float v) {
    return (v > 0.f) ? 1.f : ((v < 0.f) ? -1.f : 0.f);
}

__global__ __launch_bounds__(256) void sentinel_kernel(float* __restrict__ out, int n, float v) {
    int i = blockIdx.x * blockDim.x + threadIdx.x;
    if (i < n) out[i] = v;
}

// numpy-exact sum of squares over the channel axis (np.sum pairwise algorithm).
// C<8: sequential. C>=8 (multiple of 8 here): 8 strided accumulators, combined
// ((r0+r1)+(r2+r3)) + ((r4+r5)+(r6+r7)). All mul/add round-to-nearest, no FMA.
template <int C>
__global__ __launch_bounds__(256) void sq_np_kernel(const float* __restrict__ x, int Ctot, int c0,
                                                    float* __restrict__ sq) {
    int i = blockIdx.x * blockDim.x + threadIdx.x;
    if (i >= B * N) return;
    int b = i >> 10, n = i & (N - 1);
    const float* xb = x + ((size_t)b * Ctot + c0) * N + n;
    float res;
    if (C < 8) {
        float v0 = xb[0];
        res = __fmul_rn(v0, v0);
        for (int c = 1; c < C; ++c) {
            float v = xb[(size_t)c * N];
            res = __fadd_rn(res, __fmul_rn(v, v));
        }
    } else {
        float r[8];
#pragma unroll
        for (int j = 0; j < 8; ++j) {
            float v = xb[(size_t)j * N];
            r[j] = __fmul_rn(v, v);
        }
        for (int c = 8; c < C; c += 8) {
#pragma unroll
            for (int j = 0; j < 8; ++j) {
                float v = xb[(size_t)(c + j) * N];
                r[j] = __fadd_rn(r[j], __fmul_rn(v, v));
            }
        }
        res = __fadd_rn(__fadd_rn(__fadd_rn(r[0], r[1]), __fadd_rn(r[2], r[3])),
                        __fadd_rn(__fadd_rn(r[4], r[5]), __fadd_rn(r[6], r[7])));
    }
    sq[i] = res;
}

// One block per (b,n). Distances: np-einsum-exact f32 (sequential c, mul_rn/add_rn, no FMA),
// neg_d = ((2*inner - sq_n) - sq_m) left-associated. Stable top-20 (ties -> lower index).
template <int C>
__global__ __launch_bounds__(256) void knn_kernel(const float* __restrict__ x, int Ctot, int c0,
                                                  const float* __restrict__ sq,
                                                  int* __restrict__ idxout) {
    const int b = blockIdx.y, n = blockIdx.x, tid = threadIdx.x;
    __shared__ float xn[C];
    __shared__ float d[N];
    __shared__ float rv[256];
    __shared__ int ri[256];
    const float* xb = x + ((size_t)b * Ctot + c0) * N;
    for (int c = tid; c < C; c += 256) xn[c] = xb[(size_t)c * N + n];
    __syncthreads();
    const float sqn = sq[b * N + n];
    for (int m = tid; m < N; m += 256) {
        float acc = 0.f;
        for (int c = 0; c < C; ++c)
            acc = __fadd_rn(acc, __fmul_rn(xn[c], xb[(size_t)c * N + m]));
        d[m] = __fsub_rn(__fsub_rn(__fmul_rn(2.f, acc), sqn), sq[b * N + m]);
    }
    __syncthreads();
    int* out = idxout + ((size_t)b * N + n) * KNB;
    for (int kk = 0; kk < KNB; ++kk) {
        float bv = -3.4e38f;
        int bi = N;
        for (int m = tid; m < N; m += 256) {
            float v = d[m];
            if (v > bv) { bv = v; bi = m; }  // ascending m + strict > keeps lowest index on tie
        }
        rv[tid] = bv; ri[tid] = bi;
        __syncthreads();
        for (int s = 128; s > 0; s >>= 1) {
            if (tid < s) {
                float v2 = rv[tid + s]; int i2 = ri[tid + s];
                if (v2 > rv[tid] || (v2 == rv[tid] && i2 < ri[tid])) { rv[tid] = v2; ri[tid] = i2; }
            }
            __syncthreads();
        }
        if (tid == 0) { out[kk] = ri[0]; d[ri[0]] = -3.4e38f; }
        __syncthreads();
    }
}

// One block per (b,n), one thread per output channel o.
// BIN=false (layer 1): np-einsum-exact f32 — single sequential acc chain over the 6
// feat channels [diff0,diff1,diff2,ctr0,ctr1,ctr2], mul_rn/add_rn, no FMA.
// BIN=true: signs {-1,0,1} -> integer-exact, fast fmaf path.
template <int C, int COUT, bool BIN>
__global__ __launch_bounds__(COUT) void edgeconv_kernel(
    const float* __restrict__ xin, int Ctot_in, int c0_in, const int* __restrict__ idx,
    const float* __restrict__ W, const float* __restrict__ aa, const float* __restrict__ ssc,
    const float* __restrict__ bbi, const float* __restrict__ pp, float* __restrict__ xout,
    int c0_out) {
    const int b = blockIdx.y, n = blockIdx.x, tid = threadIdx.x;
    __shared__ float ctr_raw[C];
    __shared__ float ctr_f[C];
    __shared__ __align__(16) float df[C][KNB];
    __shared__ int ids[KNB];
    const float* xb = xin + ((size_t)b * Ctot_in + c0_in) * N;
    if (tid < KNB) ids[tid] = idx[((size_t)b * N + n) * KNB + tid];
    for (int c = tid; c < C; c += COUT) {
        float v = xb[(size_t)c * N + n];
        ctr_raw[c] = v;
        ctr_f[c] = BIN ? sgnf(v) : v;
    }
    __syncthreads();
    for (int t = tid; t < C * KNB; t += COUT) {
        int c = t / KNB, k = t - c * KNB;
        float v = __fsub_rn(xb[(size_t)c * N + ids[k]], ctr_raw[c]);  // nb - ctr, f32 round
        df[c][k] = BIN ? sgnf(v) : v;
    }
    __syncthreads();
    const int o = tid;
    const float* wrow = W + (size_t)o * (2 * C);
    const float as = __fmul_rn(aa[o], ssc[o]);
    const float bo = bbi[o], po = pp[o];
    float best = -3.4e38f;
    if (BIN) {
        float csum = 0.f;
        for (int c = 0; c < C; ++c) csum = fmaf(ctr_f[c], sgnf(wrow[C + c]), csum);
        float acc[KNB];
#pragma unroll
        for (int k = 0; k < KNB; ++k) acc[k] = 0.f;
        for (int c = 0; c < C; ++c) {
            float w = sgnf(wrow[c]);
            const float4* dp = reinterpret_cast<const float4*>(&df[c][0]);
            float4 q0 = dp[0], q1 = dp[1], q2 = dp[2], q3 = dp[3], q4 = dp[4];
            acc[0] = fmaf(q0.x, w, acc[0]);   acc[1] = fmaf(q0.y, w, acc[1]);
            acc[2] = fmaf(q0.z, w, acc[2]);   acc[3] = fmaf(q0.w, w, acc[3]);
            acc[4] = fmaf(q1.x, w, acc[4]);   acc[5] = fmaf(q1.y, w, acc[5]);
            acc[6] = fmaf(q1.z, w, acc[6]);   acc[7] = fmaf(q1.w, w, acc[7]);
            acc[8] = fmaf(q2.x, w, acc[8]);   acc[9] = fmaf(q2.y, w, acc[9]);
            acc[10] = fmaf(q2.z, w, acc[10]); acc[11] = fmaf(q2.w, w, acc[11]);
            acc[12] = fmaf(q3.x, w, acc[12]); acc[13] = fmaf(q3.y, w, acc[13]);
            acc[14] = fmaf(q3.z, w, acc[14]); acc[15] = fmaf(q3.w, w, acc[15]);
            acc[16] = fmaf(q4.x, w, acc[16]); acc[17] = fmaf(q4.y, w, acc[17]);
            acc[18] = fmaf(q4.z, w, acc[18]); acc[19] = fmaf(q4.w, w, acc[19]);
        }
#pragma unroll
        for (int k = 0; k < KNB; ++k) {
            float y = __fadd_rn(__fmul_rn(__fadd_rn(acc[k], csum), as), bo);
            y = y > 0.f ? y : __fmul_rn(po, y);
            best = fmaxf(best, y);
        }
    } else {
        float wd[C], wc[C];
        for (int c = 0; c < C; ++c) { wd[c] = sgnf(wrow[c]); wc[c] = sgnf(wrow[C + c]); }
        for (int k = 0; k < KNB; ++k) {
            float acc = 0.f;
            for (int c = 0; c < C; ++c) acc = __fadd_rn(acc, __fmul_rn(df[c][k], wd[c]));
            for (int c = 0; c < C; ++c) acc = __fadd_rn(acc, __fmul_rn(ctr_f[c], wc[c]));
            float y = __fadd_rn(__fmul_rn(acc, as), bo);
            y = y > 0.f ? y : __fmul_rn(po, y);
            best = fmaxf(best, y);
        }
    }
    xout[((size_t)b * 512 + (c0_out + o)) * N + n] = best;
}

// Tiled GEMM: Y = sign(W5)(1024x512) * sign(xcat[b])(512x1024), fused PReLU +
// per-(o, n-tile) partial max/sum pooling. Exact integer arithmetic (order-free).
__global__ __launch_bounds__(256) void conv1d_pool_kernel(
    const float* __restrict__ xcat, const float* __restrict__ w5, const float* __restrict__ aa,
    const float* __restrict__ ssc, const float* __restrict__ bbi, const float* __restrict__ pp,
    float* __restrict__ pmax, float* __restrict__ psum) {
    const int b = blockIdx.y;
    const int otile = blockIdx.x & 15;
    const int ntile = blockIdx.x >> 4;
    const int tid = threadIdx.x;
    __shared__ float As[64][65];
    __shared__ float Bs[64][65];
    __shared__ float redm[64][17];
    __shared__ float reds[64][17];
    const int to = tid & 15, tn = tid >> 4;
    const int obase = otile * 64, nbase = ntile * 64;
    float y[4][4];
#pragma unroll
    for (int i = 0; i < 4; ++i)
#pragma unroll
        for (int j = 0; j < 4; ++j) y[i][j] = 0.f;
    for (int k0 = 0; k0 < 512; k0 += 64) {
        for (int i = tid; i < 64 * 64; i += 256) {
            int r = i >> 6, cc = i & 63;
            As[r][cc] = sgnf(w5[(size_t)(obase + r) * 512 + k0 + cc]);
            Bs[r][cc] = sgnf(xcat[((size_t)b * 512 + k0 + r) * N + nbase + cc]);
        }
        __syncthreads();
        for (int kk = 0; kk < 64; ++kk) {
            float av[4], bv[4];
#pragma unroll
            for (int i = 0; i < 4; ++i) av[i] = As[to * 4 + i][kk];
#pragma unroll
            for (int j = 0; j < 4; ++j) bv[j] = Bs[kk][tn * 4 + j];
#pragma unroll
            for (int i = 0; i < 4; ++i)
#pragma unroll
                for (int j = 0; j < 4; ++j) y[i][j] = fmaf(av[i], bv[j], y[i][j]);
        }
        __syncthreads();
    }
#pragma unroll
    for (int i = 0; i < 4; ++i) {
        int o = obase + to * 4 + i;
        float as = __fmul_rn(aa[o], ssc[o]), bo = bbi[o], po = pp[o];
        float m = -3.4e38f, sum = 0.f;
#pragma unroll
        for (int j = 0; j < 4; ++j) {
            float v = __fadd_rn(__fmul_rn(y[i][j], as), bo);
            v = v > 0.f ? v : __fmul_rn(po, v);
            m = fmaxf(m, v);
            sum = __fadd_rn(sum, v);
        }
        redm[to * 4 + i][tn] = m;
        reds[to * 4 + i][tn] = sum;
    }
    __syncthreads();
    if (tid < 64) {
        float m = -3.4e38f, sum = 0.f;
        for (int t = 0; t < 16; ++t) m = fmaxf(m, redm[tid][t]);
        for (int t = 0; t < 16; ++t) sum = __fadd_rn(sum, reds[tid][t]);
        int o = obase + tid;
        pmax[((size_t)b * 1024 + o) * 16 + ntile] = m;
        psum[((size_t)b * 1024 + o) * 16 + ntile] = sum;
    }
}

__global__ __launch_bounds__(256) void pool_reduce_kernel(const float* __restrict__ pmax,
                                                          const float* __restrict__ psum,
                                                          float* __restrict__ pooled) {
    int i = blockIdx.x * blockDim.x + threadIdx.x;
    if (i >= B * 1024) return;
    int b = i >> 10, o = i & 1023;
    const float* pm = pmax + (size_t)i * 16;
    const float* ps = psum + (size_t)i * 16;
    float m = -3.4e38f, s = 0.f;
    for (int t = 0; t < 16; ++t) { m = fmaxf(m, pm[t]); s = __fadd_rn(s, ps[t]); }
    pooled[(size_t)b * 2048 + o] = m;
    pooled[(size_t)b * 2048 + 1024 + o] = __fmul_rn(s, (1.f / 1024.f));
}

__global__ __launch_bounds__(512) void lin1_kernel(const float* __restrict__ xin,
                                                   const float* __restrict__ W,
                                                   const float* __restrict__ aa,
                                                   const float* __restrict__ ssc,
                                                   const float* __restrict__ bbi,
                                                   const float* __restrict__ pp,
                                                   float* __restrict__ out) {
    int b = blockIdx.x, tid = threadIdx.x;
    __shared__ float sx[2048];
    for (int c = tid; c < 2048; c += 512) sx[c] = sgnf(xin[b * 2048 + c]);
    __syncthreads();
    int o = tid;
    const float* wrow = W + (size_t)o * 2048;
    float acc = 0.f;
    for (int c = 0; c < 2048; ++c) acc = fmaf(sx[c], sgnf(wrow[c]), acc);
    float y = __fadd_rn(__fmul_rn(acc, __fmul_rn(aa[o], ssc[o])), bbi[o]);
    out[b * 512 + o] = y > 0.f ? y : __fmul_rn(pp[o], y);
}

__global__ __launch_bounds__(256) void lin2_kernel(const float* __restrict__ xin,
                                                   const float* __restrict__ W,
                                                   const float* __restrict__ aa,
                                                   const float* __restrict__ ssc,
                                                   const float* __restrict__ bbi,
                                                   const float* __restrict__ pp,
                                                   float* __restrict__ out) {
    int b = blockIdx.x, tid = threadIdx.x;
    __shared__ float sx[512];
    for (int c = tid; c < 512; c += 256) sx[c] = sgnf(xin[b * 512 + c]);
    __syncthreads();
    int o = tid;
    const float* wrow = W + (size_t)o * 512;
    float acc = 0.f;
    for (int c = 0; c < 512; ++c) acc = fmaf(sx[c], sgnf(wrow[c]), acc);
    float y = __fadd_rn(__fmul_rn(acc, __fmul_rn(aa[o], ssc[o])), bbi[o]);
    out[b * 256 + o] = y > 0.f ? y : __fmul_rn(pp[o], y);
}

__global__ __launch_bounds__(64) void lin3_kernel(const float* __restrict__ xin,
                                                  const float* __restrict__ W,
                                                  const float* __restrict__ ssc,
                                                  const float* __restrict__ bbi,
                                                  float* __restrict__ out) {
    int b = blockIdx.x, j = threadIdx.x;
    if (j >= 40) return;
    const float* wrow = W + j * 256;
    const float* xb = xin + b * 256;
    double acc = 0.0;
    for (int c = 0; c < 256; ++c) acc = fma((double)xb[c], (double)wrow[c], acc);
    out[b * 40 + j] = __fadd_rn(__fmul_rn((float)acc, ssc[j]), bbi[j]);
}

extern "C" void kernel_launch(void* const* d_in, const int* in_sizes, int n_in, void* d_out,
                              int out_size, void* d_ws, size_t ws_size, hipStream_t stream) {
    float* outp = (float*)d_out;
    auto sentinel = [&](float code) {
        sentinel_kernel<<<(640 + 255) / 256, 256, 0, stream>>>(outp, 640, code * 1.0e6f);
    };
    if (n_in != 39) { sentinel(1.f); return; }
    static const int expect[39] = {
        16 * 3 * 1024,
        64 * 6, 64, 64, 64, 64,
        64 * 128, 64, 64, 64, 64,
        128 * 128, 128, 128, 128, 128,
        256 * 256, 256, 256, 256, 256,
        1024 * 512, 1024, 1024, 1024, 1024,
        512 * 2048, 512, 512, 512, 512,
        256 * 512, 256, 256, 256, 256,
        40 * 256, 40, 40
    };
    for (int i = 0; i < 39; ++i)
        if (in_sizes[i] != expect[i]) { sentinel(2.f); return; }
    if (out_size != 640) { sentinel(3.f); return; }

    const float* x0 = (const float*)d_in[0];
    const float *w1 = (const float*)d_in[1], *a1 = (const float*)d_in[2],
                *s1 = (const float*)d_in[3], *b1 = (const float*)d_in[4],
                *p1 = (const float*)d_in[5];
    const float *w2 = (const float*)d_in[6], *a2 = (const float*)d_in[7],
                *s2 = (const float*)d_in[8], *b2 = (const float*)d_in[9],
                *p2 = (const float*)d_in[10];
    const float *w3 = (const float*)d_in[11], *a3 = (const float*)d_in[12],
                *s3 = (const float*)d_in[13], *b3 = (const float*)d_in[14],
                *p3 = (const float*)d_in[15];
    const float *w4 = (const float*)d_in[16], *a4 = (const float*)d_in[17],
                *s4 = (const float*)d_in[18], *b4 = (const float*)d_in[19],
                *p4 = (const float*)d_in[20];
    const float *w5 = (const float*)d_in[21], *a5 = (const float*)d_in[22],
                *s5 = (const float*)d_in[23], *b5 = (const float*)d_in[24],
                *p5 = (const float*)d_in[25];
    const float *wl1 = (const float*)d_in[26], *al1 = (const float*)d_in[27],
                *sl1 = (const float*)d_in[28], *bl1 = (const float*)d_in[29],
                *pl1 = (const float*)d_in[30];
    const float *wl2 = (const float*)d_in[31], *al2 = (const float*)d_in[32],
                *sl2 = (const float*)d_in[33], *bl2 = (const float*)d_in[34],
                *pl2 = (const float*)d_in[35];
    const float *wl3 = (const float*)d_in[36], *sl3 = (const float*)d_in[37],
                *bl3 = (const float*)d_in[38];

    char* ws = (char*)d_ws;
    size_t off = 0;
    auto alloc = [&](size_t bytes) -> void* {
        void* p = ws + off;
        off += (bytes + 255) & ~(size_t)255;
        return p;
    };
    float* xcat = (float*)alloc((size_t)B * 512 * N * 4);
    int* idxb = (int*)alloc((size_t)B * N * KNB * 4);
    float* sqb = (float*)alloc((size_t)B * N * 4);
    float* pmax = (float*)alloc((size_t)B * 1024 * 16 * 4);
    float* psum = (float*)alloc((size_t)B * 1024 * 16 * 4);
    float* pooled = (float*)alloc((size_t)B * 2048 * 4);
    float* l1o = (float*)alloc((size_t)B * 512 * 4);
    float* l2o = (float*)alloc((size_t)B * 256 * 4);
    if (off > ws_size) { sentinel(4.f); return; }

    dim3 gnb(N, B);
    // layer 1: knn on x0 (C=3), conv 6->64 (np-exact f32) -> xcat[:, 0:64, :]
    sq_np_kernel<3><<<(B * N + 255) / 256, 256, 0, stream>>>(x0, 3, 0, sqb);
    knn_kernel<3><<<gnb, 256, 0, stream>>>(x0, 3, 0, sqb, idxb);
    edgeconv_kernel<3, 64, false>
        <<<gnb, 64, 0, stream>>>(x0, 3, 0, idxb, w1, a1, s1, b1, p1, xcat, 0);
    // layer 2: knn on x1 (C=64), conv 128->64 -> xcat[:, 64:128, :]
    sq_np_kernel<64><<<(B * N + 255) / 256, 256, 0, stream>>>(xcat, 512, 0, sqb);
    knn_kernel<64><<<gnb, 256, 0, stream>>>(xcat, 512, 0, sqb, idxb);
    edgeconv_kernel<64, 64, true>
        <<<gnb, 64, 0, stream>>>(xcat, 512, 0, idxb, w2, a2, s2, b2, p2, xcat, 64);
    // layer 3: knn on x2 (C=64), conv 128->128 -> xcat[:, 128:256, :]
    sq_np_kernel<64><<<(B * N + 255) / 256, 256, 0, stream>>>(xcat, 512, 64, sqb);
    knn_kernel<64><<<gnb, 256, 0, stream>>>(xcat, 512, 64, sqb, idxb);
    edgeconv_kernel<64, 128, true>
        <<<gnb, 128, 0, stream>>>(xcat, 512, 64, idxb, w3, a3, s3, b3, p3, xcat, 128);
    // layer 4: knn on x3 (C=128), conv 256->256 -> xcat[:, 256:512, :]
    sq_np_kernel<128><<<(B * N + 255) / 256, 256, 0, stream>>>(xcat, 512, 128, sqb);
    knn_kernel<128><<<gnb, 256, 0, stream>>>(xcat, 512, 128, sqb, idxb);
    edgeconv_kernel<128, 256, true>
        <<<gnb, 256, 0, stream>>>(xcat, 512, 128, idxb, w4, a4, s4, b4, p4, xcat, 256);
    // conv1d 512->1024 + PReLU + pooling (exact integer)
    conv1d_pool_kernel<<<dim3(256, B), 256, 0, stream>>>(xcat, w5, a5, s5, b5, p5, pmax, psum);
    pool_reduce_kernel<<<(B * 1024 + 255) / 256, 256, 0, stream>>>(pmax, psum, pooled);
    lin1_kernel<<<B, 512, 0, stream>>>(pooled, wl1, al1, sl1, bl1, pl1, l1o);
    lin2_kernel<<<B, 256, 0, stream>>>(l1o, wl2, al2, sl2, bl2, pl2, l2o);
    lin3_kernel<<<B, 64, 0, stream>>>(l2o, wl3, sl3, bl3, outp);
}

// Round 6
// 2468.694 us; speedup vs baseline: 1.4554x; 1.4554x over previous
//
#include <hip/hip_runtime.h>
#include <math.h>

#define B 16
#define N 1024
#define KNB 20

typedef unsigned int u32;
typedef unsigned long long u64;

__device__ __forceinline__ float sgnf(float v) {
    return (v > 0.f) ? 1.f : ((v < 0.f) ? -1.f : 0.f);
}

__global__ __launch_bounds__(256) void sentinel_kernel(float* __restrict__ out, int n, float v) {
    int i = blockIdx.x * blockDim.x + threadIdx.x;
    if (i < n) out[i] = v;
}

// ---------------- np-exact knn path (UNCHANGED from passing round) ----------------

template <int C>
__global__ __launch_bounds__(256) void sq_np_kernel(const float* __restrict__ x, int Ctot, int c0,
                                                    float* __restrict__ sq) {
    int i = blockIdx.x * blockDim.x + threadIdx.x;
    if (i >= B * N) return;
    int b = i >> 10, n = i & (N - 1);
    const float* xb = x + ((size_t)b * Ctot + c0) * N + n;
    float res;
    if (C < 8) {
        float v0 = xb[0];
        res = __fmul_rn(v0, v0);
        for (int c = 1; c < C; ++c) {
            float v = xb[(size_t)c * N];
            res = __fadd_rn(res, __fmul_rn(v, v));
        }
    } else {
        float r[8];
#pragma unroll
        for (int j = 0; j < 8; ++j) {
            float v = xb[(size_t)j * N];
            r[j] = __fmul_rn(v, v);
        }
        for (int c = 8; c < C; c += 8) {
#pragma unroll
            for (int j = 0; j < 8; ++j) {
                float v = xb[(size_t)(c + j) * N];
                r[j] = __fadd_rn(r[j], __fmul_rn(v, v));
            }
        }
        res = __fadd_rn(__fadd_rn(__fadd_rn(r[0], r[1]), __fadd_rn(r[2], r[3])),
                        __fadd_rn(__fadd_rn(r[4], r[5]), __fadd_rn(r[6], r[7])));
    }
    sq[i] = res;
}

template <int C>
__global__ __launch_bounds__(256) void knn_kernel(const float* __restrict__ x, int Ctot, int c0,
                                                  const float* __restrict__ sq,
                                                  int* __restrict__ idxout) {
    const int b = blockIdx.y, n = blockIdx.x, tid = threadIdx.x;
    __shared__ float xn[C];
    __shared__ float d[N];
    __shared__ float rv[256];
    __shared__ int ri[256];
    const float* xb = x + ((size_t)b * Ctot + c0) * N;
    for (int c = tid; c < C; c += 256) xn[c] = xb[(size_t)c * N + n];
    __syncthreads();
    const float sqn = sq[b * N + n];
    for (int m = tid; m < N; m += 256) {
        float acc = 0.f;
        for (int c = 0; c < C; ++c)
            acc = __fadd_rn(acc, __fmul_rn(xn[c], xb[(size_t)c * N + m]));
        d[m] = __fsub_rn(__fsub_rn(__fmul_rn(2.f, acc), sqn), sq[b * N + m]);
    }
    __syncthreads();
    int* out = idxout + ((size_t)b * N + n) * KNB;
    for (int kk = 0; kk < KNB; ++kk) {
        float bv = -3.4e38f;
        int bi = N;
        for (int m = tid; m < N; m += 256) {
            float v = d[m];
            if (v > bv) { bv = v; bi = m; }
        }
        rv[tid] = bv; ri[tid] = bi;
        __syncthreads();
        for (int s = 128; s > 0; s >>= 1) {
            if (tid < s) {
                float v2 = rv[tid + s]; int i2 = ri[tid + s];
                if (v2 > rv[tid] || (v2 == rv[tid] && i2 < ri[tid])) { rv[tid] = v2; ri[tid] = i2; }
            }
            __syncthreads();
        }
        if (tid == 0) { out[kk] = ri[0]; d[ri[0]] = -3.4e38f; }
        __syncthreads();
    }
}

// ---------------- layer-1 edgeconv (np-exact, UNCHANGED) ----------------

template <int C, int COUT>
__global__ __launch_bounds__(COUT) void edgeconv1_kernel(
    const float* __restrict__ xin, int Ctot_in, int c0_in, const int* __restrict__ idx,
    const float* __restrict__ W, const float* __restrict__ aa, const float* __restrict__ ssc,
    const float* __restrict__ bbi, const float* __restrict__ pp, float* __restrict__ xout,
    int c0_out) {
    const int b = blockIdx.y, n = blockIdx.x, tid = threadIdx.x;
    __shared__ float ctr_raw[C];
    __shared__ float ctr_f[C];
    __shared__ __align__(16) float df[C][KNB];
    __shared__ int ids[KNB];
    const float* xb = xin + ((size_t)b * Ctot_in + c0_in) * N;
    if (tid < KNB) ids[tid] = idx[((size_t)b * N + n) * KNB + tid];
    for (int c = tid; c < C; c += COUT) {
        float v = xb[(size_t)c * N + n];
        ctr_raw[c] = v;
        ctr_f[c] = v;
    }
    __syncthreads();
    for (int t = tid; t < C * KNB; t += COUT) {
        int c = t / KNB, k = t - c * KNB;
        df[c][k] = __fsub_rn(xb[(size_t)c * N + ids[k]], ctr_raw[c]);
    }
    __syncthreads();
    const int o = tid;
    const float* wrow = W + (size_t)o * (2 * C);
    const float as = __fmul_rn(aa[o], ssc[o]);
    const float bo = bbi[o], po = pp[o];
    float best = -3.4e38f;
    float wd[C], wc[C];
    for (int c = 0; c < C; ++c) { wd[c] = sgnf(wrow[c]); wc[c] = sgnf(wrow[C + c]); }
    for (int k = 0; k < KNB; ++k) {
        float acc = 0.f;
        for (int c = 0; c < C; ++c) acc = __fadd_rn(acc, __fmul_rn(df[c][k], wd[c]));
        for (int c = 0; c < C; ++c) acc = __fadd_rn(acc, __fmul_rn(ctr_f[c], wc[c]));
        float y = __fadd_rn(__fmul_rn(acc, as), bo);
        y = y > 0.f ? y : __fmul_rn(po, y);
        best = fmaxf(best, y);
    }
    xout[((size_t)b * 512 + (c0_out + o)) * N + n] = best;
}

// ---------------- ternary bitpack helpers ----------------

// pack per-row sign/nonzero masks; cols multiple of 32
__global__ __launch_bounds__(256) void pack_rows_kernel(const float* __restrict__ src, int rows,
                                                        int cols, u32* __restrict__ s,
                                                        u32* __restrict__ nz) {
    int i = blockIdx.x * blockDim.x + threadIdx.x;
    int wpr = cols >> 5;
    if (i >= rows * wpr) return;
    int r = i / wpr, w = i - r * wpr;
    const float* p = src + (size_t)r * cols + (size_t)w * 32;
    u32 sb = 0, nb = 0;
    for (int j = 0; j < 32; ++j) {
        float v = p[j];
        if (v < 0.f) sb |= (1u << j);
        if (v != 0.f) nb |= (1u << j);
    }
    s[i] = sb;
    nz[i] = nb;
}

// pack xcat channel-signs into bit planes: out[(b*16+w)*N + n], bit j = ch w*32+j of (b,n)
__global__ __launch_bounds__(256) void pack_cols_kernel(const float* __restrict__ x,
                                                        u32* __restrict__ s,
                                                        u32* __restrict__ nz) {
    int i = blockIdx.x * blockDim.x + threadIdx.x;
    if (i >= B * 16 * N) return;
    int n = i & (N - 1);
    int w = (i >> 10) & 15;
    int b = i >> 14;
    const float* p = x + ((size_t)b * 512 + (size_t)w * 32) * N + n;
    u32 sb = 0, nb = 0;
    for (int j = 0; j < 32; ++j) {
        float v = p[(size_t)j * N];
        if (v < 0.f) sb |= (1u << j);
        if (v != 0.f) nb |= (1u << j);
    }
    s[i] = sb;
    nz[i] = nb;
}

// ---------------- binarized edgeconv via xor/popcount (exact integer) ----------------

template <int C, int COUT>
__global__ __launch_bounds__(COUT) void edgeconv_bin_kernel(
    const float* __restrict__ xin, int Ctot_in, int c0_in, const int* __restrict__ idx,
    const u32* __restrict__ wsm, const u32* __restrict__ wnzm, const float* __restrict__ aa,
    const float* __restrict__ ssc, const float* __restrict__ bbi, const float* __restrict__ pp,
    float* __restrict__ xout, int c0_out) {
    constexpr int W = C / 32;
    const int b = blockIdx.y, n = blockIdx.x, tid = threadIdx.x;
    __shared__ float ctr_raw[C];
    __shared__ int ids[KNB];
    __shared__ u32 ctr_s[W], ctr_nz[W];
    __shared__ u32 dfs[KNB][W], dfnz[KNB][W];
    const float* xb = xin + ((size_t)b * Ctot_in + c0_in) * N;
    if (tid < KNB) ids[tid] = idx[((size_t)b * N + n) * KNB + tid];
    // phase A: center column floats + ternary masks (wave-aligned ballots: 64 | C)
    if (tid < C) {
        float v = xb[(size_t)tid * N + n];
        ctr_raw[tid] = v;
        u64 bs = __ballot(v < 0.f);
        u64 bnz = __ballot(v != 0.f);
        if ((tid & 63) == 0) {
            int wb = tid >> 5;
            ctr_s[wb] = (u32)bs;       ctr_s[wb + 1] = (u32)(bs >> 32);
            ctr_nz[wb] = (u32)bnz;     ctr_nz[wb + 1] = (u32)(bnz >> 32);
        }
    }
    __syncthreads();
    // phase B: per-edge diff-sign masks (each wave covers a 64-aligned c range of one k)
    for (int t = tid; t < KNB * C; t += COUT) {
        int k = t / C, c = t - k * C;
        float v = __fsub_rn(xb[(size_t)c * N + ids[k]], ctr_raw[c]);
        u64 bs = __ballot(v < 0.f);
        u64 bnz = __ballot(v != 0.f);
        if ((c & 63) == 0) {
            int wb = c >> 5;
            dfs[k][wb] = (u32)bs;      dfs[k][wb + 1] = (u32)(bs >> 32);
            dfnz[k][wb] = (u32)bnz;    dfnz[k][wb + 1] = (u32)(bnz >> 32);
        }
    }
    __syncthreads();
    // phase C: popcount dot per output channel; dot == old fmaf integer exactly
    const int o = tid;
    const u32* wsrow = wsm + (size_t)o * 2 * W;
    const u32* wnzrow = wnzm + (size_t)o * 2 * W;
    u32 wds[W], wdnz[W], wcs[W], wcnz[W];
#pragma unroll
    for (int w = 0; w < W; ++w) {
        wds[w] = wsrow[w];      wcs[w] = wsrow[W + w];
        wdnz[w] = wnzrow[w];    wcnz[w] = wnzrow[W + w];
    }
    int cdot = 0;
#pragma unroll
    for (int w = 0; w < W; ++w) {
        u32 nzb = ctr_nz[w] & wcnz[w];
        u32 neg = (ctr_s[w] ^ wcs[w]) & nzb;
        cdot += __popc(nzb) - 2 * __popc(neg);
    }
    const float as = __fmul_rn(aa[o], ssc[o]);
    const float bo = bbi[o], po = pp[o];
    float best = -3.4e38f;
    for (int k = 0; k < KNB; ++k) {
        int dot = cdot;
#pragma unroll
        for (int w = 0; w < W; ++w) {
            u32 nzb = dfnz[k][w] & wdnz[w];
            u32 neg = (dfs[k][w] ^ wds[w]) & nzb;
            dot += __popc(nzb) - 2 * __popc(neg);
        }
        float y = __fadd_rn(__fmul_rn((float)dot, as), bo);
        y = y > 0.f ? y : __fmul_rn(po, y);
        best = fmaxf(best, y);
    }
    xout[((size_t)b * 512 + (c0_out + o)) * N + n] = best;
}

// ---------------- conv1d as bitplane popcount GEMM + fused pooling ----------------
// block: 256 threads, each owns output channel o = otile*256+tid; 256 n per block.
__global__ __launch_bounds__(256) void conv1d_bin_pool_kernel(
    const u32* __restrict__ xs, const u32* __restrict__ xnz, const u32* __restrict__ w5s,
    const u32* __restrict__ w5nz, const float* __restrict__ aa, const float* __restrict__ ssc,
    const float* __restrict__ bbi, const float* __restrict__ pp, float* __restrict__ pmax,
    float* __restrict__ psum) {
    const int b = blockIdx.y;
    const int otile = blockIdx.x & 3;
    const int nq = blockIdx.x >> 2;
    const int tid = threadIdx.x;
    const int o = otile * 256 + tid;
    __shared__ u32 shs[128][20];   // padded to break bank alignment
    __shared__ u32 shnz[128][20];
    u32 ws[16], wnz[16];
#pragma unroll
    for (int w = 0; w < 16; ++w) {
        ws[w] = w5s[(size_t)o * 16 + w];
        wnz[w] = w5nz[(size_t)o * 16 + w];
    }
    const float as = __fmul_rn(aa[o], ssc[o]);
    const float bo = bbi[o], po = pp[o];
    float m = -3.4e38f, sum = 0.f;
    for (int half = 0; half < 2; ++half) {
        const int nbase = nq * 256 + half * 128;
        __syncthreads();
        for (int t = tid; t < 16 * 128; t += 256) {
            int w = t >> 7, nl = t & 127;
            shs[nl][w] = xs[((size_t)b * 16 + w) * N + nbase + nl];
            shnz[nl][w] = xnz[((size_t)b * 16 + w) * N + nbase + nl];
        }
        __syncthreads();
        for (int nl = 0; nl < 128; ++nl) {
            int dot = 0;
#pragma unroll
            for (int w = 0; w < 16; ++w) {
                u32 nzb = shnz[nl][w] & wnz[w];
                u32 neg = (shs[nl][w] ^ ws[w]) & nzb;
                dot += __popc(nzb) - 2 * __popc(neg);
            }
            float y = __fadd_rn(__fmul_rn((float)dot, as), bo);
            y = y > 0.f ? y : __fmul_rn(po, y);
            m = fmaxf(m, y);
            sum = __fadd_rn(sum, y);  // exact: quarter-integers
        }
    }
    pmax[((size_t)b * 1024 + o) * 4 + nq] = m;
    psum[((size_t)b * 1024 + o) * 4 + nq] = sum;
}

__global__ __launch_bounds__(256) void pool_reduce_kernel(const float* __restrict__ pmax,
                                                          const float* __restrict__ psum,
                                                          float* __restrict__ pooled) {
    int i = blockIdx.x * blockDim.x + threadIdx.x;
    if (i >= B * 1024) return;
    int b = i >> 10, o = i & 1023;
    const float* pm = pmax + (size_t)i * 4;
    const float* ps = psum + (size_t)i * 4;
    float m = -3.4e38f, s = 0.f;
    for (int t = 0; t < 4; ++t) { m = fmaxf(m, pm[t]); s = __fadd_rn(s, ps[t]); }
    pooled[(size_t)b * 2048 + o] = m;
    pooled[(size_t)b * 2048 + 1024 + o] = __fmul_rn(s, (1.f / 1024.f));
}

// ---------------- heads (UNCHANGED) ----------------

__global__ __launch_bounds__(512) void lin1_kernel(const float* __restrict__ xin,
                                                   const float* __restrict__ W,
                                                   const float* __restrict__ aa,
                                                   const float* __restrict__ ssc,
                                                   const float* __restrict__ bbi,
                                                   const float* __restrict__ pp,
                                                   float* __restrict__ out) {
    int b = blockIdx.x, tid = threadIdx.x;
    __shared__ float sx[2048];
    for (int c = tid; c < 2048; c += 512) sx[c] = sgnf(xin[b * 2048 + c]);
    __syncthreads();
    int o = tid;
    const float* wrow = W + (size_t)o * 2048;
    float acc = 0.f;
    for (int c = 0; c < 2048; ++c) acc = fmaf(sx[c], sgnf(wrow[c]), acc);
    float y = __fadd_rn(__fmul_rn(acc, __fmul_rn(aa[o], ssc[o])), bbi[o]);
    out[b * 512 + o] = y > 0.f ? y : __fmul_rn(pp[o], y);
}

__global__ __launch_bounds__(256) void lin2_kernel(const float* __restrict__ xin,
                                                   const float* __restrict__ W,
                                                   const float* __restrict__ aa,
                                                   const float* __restrict__ ssc,
                                                   const float* __restrict__ bbi,
                                                   const float* __restrict__ pp,
                                                   float* __restrict__ out) {
    int b = blockIdx.x, tid = threadIdx.x;
    __shared__ float sx[512];
    for (int c = tid; c < 512; c += 256) sx[c] = sgnf(xin[b * 512 + c]);
    __syncthreads();
    int o = tid;
    const float* wrow = W + (size_t)o * 512;
    float acc = 0.f;
    for (int c = 0; c < 512; ++c) acc = fmaf(sx[c], sgnf(wrow[c]), acc);
    float y = __fadd_rn(__fmul_rn(acc, __fmul_rn(aa[o], ssc[o])), bbi[o]);
    out[b * 256 + o] = y > 0.f ? y : __fmul_rn(pp[o], y);
}

__global__ __launch_bounds__(64) void lin3_kernel(const float* __restrict__ xin,
                                                  const float* __restrict__ W,
                                                  const float* __restrict__ ssc,
                                                  const float* __restrict__ bbi,
                                                  float* __restrict__ out) {
    int b = blockIdx.x, j = threadIdx.x;
    if (j >= 40) return;
    const float* wrow = W + j * 256;
    const float* xb = xin + b * 256;
    double acc = 0.0;
    for (int c = 0; c < 256; ++c) acc = fma((double)xb[c], (double)wrow[c], acc);
    out[b * 40 + j] = __fadd_rn(__fmul_rn((float)acc, ssc[j]), bbi[j]);
}

extern "C" void kernel_launch(void* const* d_in, const int* in_sizes, int n_in, void* d_out,
                              int out_size, void* d_ws, size_t ws_size, hipStream_t stream) {
    float* outp = (float*)d_out;
    auto sentinel = [&](float code) {
        sentinel_kernel<<<(640 + 255) / 256, 256, 0, stream>>>(outp, 640, code * 1.0e6f);
    };
    if (n_in != 39) { sentinel(1.f); return; }
    static const int expect[39] = {
        16 * 3 * 1024,
        64 * 6, 64, 64, 64, 64,
        64 * 128, 64, 64, 64, 64,
        128 * 128, 128, 128, 128, 128,
        256 * 256, 256, 256, 256, 256,
        1024 * 512, 1024, 1024, 1024, 1024,
        512 * 2048, 512, 512, 512, 512,
        256 * 512, 256, 256, 256, 256,
        40 * 256, 40, 40
    };
    for (int i = 0; i < 39; ++i)
        if (in_sizes[i] != expect[i]) { sentinel(2.f); return; }
    if (out_size != 640) { sentinel(3.f); return; }

    const float* x0 = (const float*)d_in[0];
    const float *w1 = (const float*)d_in[1], *a1 = (const float*)d_in[2],
                *s1 = (const float*)d_in[3], *b1 = (const float*)d_in[4],
                *p1 = (const float*)d_in[5];
    const float *w2 = (const float*)d_in[6], *a2 = (const float*)d_in[7],
                *s2 = (const float*)d_in[8], *b2 = (const float*)d_in[9],
                *p2 = (const float*)d_in[10];
    const float *w3 = (const float*)d_in[11], *a3 = (const float*)d_in[12],
                *s3 = (const float*)d_in[13], *b3 = (const float*)d_in[14],
                *p3 = (const float*)d_in[15];
    const float *w4 = (const float*)d_in[16], *a4 = (const float*)d_in[17],
                *s4 = (const float*)d_in[18], *b4 = (const float*)d_in[19],
                *p4 = (const float*)d_in[20];
    const float *w5 = (const float*)d_in[21], *a5 = (const float*)d_in[22],
                *s5 = (const float*)d_in[23], *b5 = (const float*)d_in[24],
                *p5 = (const float*)d_in[25];
    const float *wl1 = (const float*)d_in[26], *al1 = (const float*)d_in[27],
                *sl1 = (const float*)d_in[28], *bl1 = (const float*)d_in[29],
                *pl1 = (const float*)d_in[30];
    const float *wl2 = (const float*)d_in[31], *al2 = (const float*)d_in[32],
                *sl2 = (const float*)d_in[33], *bl2 = (const float*)d_in[34],
                *pl2 = (const float*)d_in[35];
    const float *wl3 = (const float*)d_in[36], *sl3 = (const float*)d_in[37],
                *bl3 = (const float*)d_in[38];

    char* ws = (char*)d_ws;
    size_t off = 0;
    auto alloc = [&](size_t bytes) -> void* {
        void* p = ws + off;
        off += (bytes + 255) & ~(size_t)255;
        return p;
    };
    float* xcat = (float*)alloc((size_t)B * 512 * N * 4);
    int* idxb = (int*)alloc((size_t)B * N * KNB * 4);
    float* sqb = (float*)alloc((size_t)B * N * 4);
    u32* w2s_ = (u32*)alloc(64 * 4 * 4);     u32* w2nz_ = (u32*)alloc(64 * 4 * 4);
    u32* w3s_ = (u32*)alloc(128 * 4 * 4);    u32* w3nz_ = (u32*)alloc(128 * 4 * 4);
    u32* w4s_ = (u32*)alloc(256 * 8 * 4);    u32* w4nz_ = (u32*)alloc(256 * 8 * 4);
    u32* w5s_ = (u32*)alloc(1024 * 16 * 4);  u32* w5nz_ = (u32*)alloc(1024 * 16 * 4);
    u32* xss = (u32*)alloc((size_t)B * 16 * N * 4);
    u32* xnzs = (u32*)alloc((size_t)B * 16 * N * 4);
    float* pmax = (float*)alloc((size_t)B * 1024 * 4 * 4);
    float* psum = (float*)alloc((size_t)B * 1024 * 4 * 4);
    float* pooled = (float*)alloc((size_t)B * 2048 * 4);
    float* l1o = (float*)alloc((size_t)B * 512 * 4);
    float* l2o = (float*)alloc((size_t)B * 256 * 4);
    if (off > ws_size) { sentinel(4.f); return; }

    // pack weight masks (tiny)
    pack_rows_kernel<<<1, 256, 0, stream>>>(w2, 64, 128, w2s_, w2nz_);
    pack_rows_kernel<<<2, 256, 0, stream>>>(w3, 128, 128, w3s_, w3nz_);
    pack_rows_kernel<<<8, 256, 0, stream>>>(w4, 256, 256, w4s_, w4nz_);
    pack_rows_kernel<<<64, 256, 0, stream>>>(w5, 1024, 512, w5s_, w5nz_);

    dim3 gnb(N, B);
    // layer 1: knn on x0 (C=3), conv 6->64 (np-exact f32) -> xcat[:, 0:64, :]
    sq_np_kernel<3><<<(B * N + 255) / 256, 256, 0, stream>>>(x0, 3, 0, sqb);
    knn_kernel<3><<<gnb, 256, 0, stream>>>(x0, 3, 0, sqb, idxb);
    edgeconv1_kernel<3, 64>
        <<<gnb, 64, 0, stream>>>(x0, 3, 0, idxb, w1, a1, s1, b1, p1, xcat, 0);
    // layer 2: knn on x1 (C=64), bin conv 128->64 -> xcat[:, 64:128, :]
    sq_np_kernel<64><<<(B * N + 255) / 256, 256, 0, stream>>>(xcat, 512, 0, sqb);
    knn_kernel<64><<<gnb, 256, 0, stream>>>(xcat, 512, 0, sqb, idxb);
    edgeconv_bin_kernel<64, 64>
        <<<gnb, 64, 0, stream>>>(xcat, 512, 0, idxb, w2s_, w2nz_, a2, s2, b2, p2, xcat, 64);
    // layer 3
    sq_np_kernel<64><<<(B * N + 255) / 256, 256, 0, stream>>>(xcat, 512, 64, sqb);
    knn_kernel<64><<<gnb, 256, 0, stream>>>(xcat, 512, 64, sqb, idxb);
    edgeconv_bin_kernel<64, 128>
        <<<gnb, 128, 0, stream>>>(xcat, 512, 64, idxb, w3s_, w3nz_, a3, s3, b3, p3, xcat, 128);
    // layer 4
    sq_np_kernel<128><<<(B * N + 255) / 256, 256, 0, stream>>>(xcat, 512, 128, sqb);
    knn_kernel<128><<<gnb, 256, 0, stream>>>(xcat, 512, 128, sqb, idxb);
    edgeconv_bin_kernel<128, 256>
        <<<gnb, 256, 0, stream>>>(xcat, 512, 128, idxb, w4s_, w4nz_, a4, s4, b4, p4, xcat, 256);
    // conv1d (bitplane popcount) + fused pooling
    pack_cols_kernel<<<(B * 16 * N + 255) / 256, 256, 0, stream>>>(xcat, xss, xnzs);
    conv1d_bin_pool_kernel<<<dim3(16, B), 256, 0, stream>>>(xss, xnzs, w5s_, w5nz_, a5, s5, b5,
                                                            p5, pmax, psum);
    pool_reduce_kernel<<<(B * 1024 + 255) / 256, 256, 0, stream>>>(pmax, psum, pooled);
    // heads
    lin1_kernel<<<B, 512, 0, stream>>>(pooled, wl1, al1, sl1, bl1, pl1, l1o);
    lin2_kernel<<<B, 256, 0, stream>>>(l1o, wl2, al2, sl2, bl2, pl2, l2o);
    lin3_kernel<<<B, 64, 0, stream>>>(l2o, wl3, sl3, bl3, outp);
}